// Round 1
// baseline (2737.390 us; speedup 1.0000x reference)
//
#include <hip/hip_runtime.h>
#include <stdint.h>

#define B_TOK 8192
#define DMODEL 2048
#define NDIR 32768
#define KTOP 32
#define CAP 512
#define NREF 64
#define THRESH 2.5f

typedef __attribute__((ext_vector_type(8))) short short8;
typedef __attribute__((ext_vector_type(4))) float f32x4;

__device__ __forceinline__ uint16_t f2bf(float f) {
  uint32_t u = __float_as_uint(f);
  u = (u + 0x7fffu + ((u >> 16) & 1u)) >> 16;
  return (uint16_t)u;
}
__device__ __forceinline__ float bf2f(uint32_t u) { return __uint_as_float(u << 16); }

__device__ __forceinline__ void async_load16(const void* g, void* l) {
  __builtin_amdgcn_global_load_lds(
      (const __attribute__((address_space(1))) unsigned int*)g,
      (__attribute__((address_space(3))) unsigned int*)l, 16, 0, 0);
}

// ---------------- prep: fp32 -> bf16 ----------------
__global__ void prep_x_k(const float* __restrict__ x, const float* __restrict__ pre_bias,
                         uint16_t* __restrict__ xh) {
  size_t i = ((size_t)blockIdx.x * blockDim.x + threadIdx.x) * 4;
  float4 v = *reinterpret_cast<const float4*>(x + i);
  int d = (int)(i & (DMODEL - 1));
  float4 p = *reinterpret_cast<const float4*>(pre_bias + d);
  ushort4 o;
  o.x = f2bf(v.x - p.x); o.y = f2bf(v.y - p.y);
  o.z = f2bf(v.z - p.z); o.w = f2bf(v.w - p.w);
  *reinterpret_cast<ushort4*>(xh + i) = o;
}

__global__ void prep_w_k(const float* __restrict__ w, uint16_t* __restrict__ wh) {
  size_t i = ((size_t)blockIdx.x * blockDim.x + threadIdx.x) * 4;
  float4 v = *reinterpret_cast<const float4*>(w + i);
  ushort4 o;
  o.x = f2bf(v.x); o.y = f2bf(v.y); o.z = f2bf(v.z); o.w = f2bf(v.w);
  *reinterpret_cast<ushort4*>(wh + i) = o;
}

// ---------------- bf16 GEMM (m97-style 128x128, BK=32) + threshold collect ----------------
__global__ __launch_bounds__(256) void gemm_topk(
    const uint16_t* __restrict__ xh, const uint16_t* __restrict__ wh,
    const float* __restrict__ latent_bias,
    float* __restrict__ cand_val, int* __restrict__ cand_idx, int* __restrict__ cand_cnt) {
  __shared__ uint16_t As[128 * 32];
  __shared__ uint16_t Bs[128 * 32];
  const int tid = threadIdx.x;
  const int w = tid >> 6, l = tid & 63;

  const int nbx = NDIR / 128;  // 256
  int bid = blockIdx.x;
  int swz = (bid & 7) * (((B_TOK / 128) * nbx) / 8) + (bid >> 3);  // XCD-aware, bijective (nwg%8==0)
  int bm = swz / nbx, bn = swz % nbx;
  const size_t m0 = (size_t)bm * 128, n0 = (size_t)bn * 128;

  const char* Ab = (const char*)(xh + m0 * DMODEL);
  const char* Bb = (const char*)(wh + n0 * DMODEL);

  f32x4 acc[4][4] = {};

  const int wm = (w >> 1) * 64, wn = (w & 1) * 64;
  const int lr = l & 15;
  const int lk = (l >> 4) * 16;  // byte offset of this lane's k-slice within a 64B row

  for (int kt = 0; kt < DMODEL; kt += 32) {
    // stage A/B tiles (8KB each): 8 chunks of 1KB; wave w does chunks {w, w+4}
#pragma unroll
    for (int cc = 0; cc < 2; ++cc) {
      int c = w + cc * 4;
      int lo = c * 1024 + l * 16;
      int row = lo >> 6, col = lo & 63;
      size_t goff = (size_t)row * (DMODEL * 2) + (size_t)kt * 2 + (size_t)col;
      async_load16(Ab + goff, (char*)As + c * 1024);
      async_load16(Bb + goff, (char*)Bs + c * 1024);
    }
    __syncthreads();
    short8 a[4], b[4];
#pragma unroll
    for (int f = 0; f < 4; ++f) {
      a[f] = *reinterpret_cast<const short8*>((const char*)As + (wm + f * 16 + lr) * 64 + lk);
      b[f] = *reinterpret_cast<const short8*>((const char*)Bs + (wn + f * 16 + lr) * 64 + lk);
    }
#pragma unroll
    for (int fm = 0; fm < 4; ++fm)
#pragma unroll
      for (int fn = 0; fn < 4; ++fn)
        acc[fm][fn] = __builtin_amdgcn_mfma_f32_16x16x32_bf16(a[fm], b[fn], acc[fm][fn], 0, 0, 0);
    __syncthreads();
  }

  // epilogue: C/D layout col = lane&15 (n), row = (lane>>4)*4 + j (m)
  const int lq = l >> 4;
#pragma unroll
  for (int fn = 0; fn < 4; ++fn) {
    int gn = (int)n0 + wn + fn * 16 + lr;
    float lb = latent_bias[gn];
#pragma unroll
    for (int fm = 0; fm < 4; ++fm) {
      int gmb = (int)m0 + wm + fm * 16 + lq * 4;
#pragma unroll
      for (int j = 0; j < 4; ++j) {
        float v = acc[fm][fn][j] + lb;
        if (v > THRESH) {
          int gm = gmb + j;
          int pos = atomicAdd(&cand_cnt[gm], 1);
          if (pos < CAP) {
            cand_val[(size_t)gm * CAP + pos] = v;
            cand_idx[(size_t)gm * CAP + pos] = gn;
          }
        }
      }
    }
  }
}

// ---------------- per-row: sort candidates, fp64-refine top-64, emit exact top-32 ----------------
__global__ __launch_bounds__(256) void select_refine(
    const float* __restrict__ x, const float* __restrict__ pre_bias,
    const float* __restrict__ enc_w, const float* __restrict__ latent_bias,
    const float* __restrict__ cand_val, const int* __restrict__ cand_idx,
    const int* __restrict__ cand_cnt,
    float* __restrict__ sel_val, int* __restrict__ sel_idx) {
  __shared__ float sv[CAP];
  __shared__ int si[CAP];
  __shared__ float xc[DMODEL];
  __shared__ double red[4];
  __shared__ double rv[NREF];
  __shared__ int ri[NREF];

  const int row = blockIdx.x, tid = threadIdx.x;

  for (int d = tid; d < DMODEL; d += 256)
    xc[d] = x[(size_t)row * DMODEL + d] - pre_bias[d];

  int c = cand_cnt[row];
  if (c > CAP) c = CAP;
  for (int i = tid; i < CAP; i += 256) {
    if (i < c) {
      sv[i] = cand_val[(size_t)row * CAP + i];
      si[i] = cand_idx[(size_t)row * CAP + i];
    } else {
      sv[i] = -1e30f;
      si[i] = 0x7fffffff;
    }
  }

  // bitonic sort, descending by (val, then lower idx) — deterministic despite atomic append order
  for (int k = 2; k <= CAP; k <<= 1) {
    for (int j = k >> 1; j > 0; j >>= 1) {
      __syncthreads();
      int i = ((tid & ~(j - 1)) << 1) | (tid & (j - 1));
      int p = i | j;
      bool up = ((i & k) == 0);
      float va = sv[i], vb = sv[p];
      int ia = si[i], ib = si[p];
      bool aFirst = (va > vb) || (va == vb && ia < ib);
      if (up ? (!aFirst) : aFirst) {
        sv[i] = vb; sv[p] = va; si[i] = ib; si[p] = ia;
      }
    }
  }
  __syncthreads();

  const int nref = c < NREF ? c : NREF;
  for (int jc = 0; jc < NREF; ++jc) {
    if (jc < nref) {  // uniform branch
      int n = si[jc];
      const float* wrow = enc_w + (size_t)n * DMODEL;
      double s = 0.0;
      for (int d = tid; d < DMODEL; d += 256)
        s += (double)xc[d] * (double)wrow[d];
#pragma unroll
      for (int off = 32; off > 0; off >>= 1)
        s += __shfl_down(s, off);
      if ((tid & 63) == 0) red[tid >> 6] = s;
      __syncthreads();
      if (tid == 0) {
        rv[jc] = red[0] + red[1] + red[2] + red[3] + (double)latent_bias[n];
        ri[jc] = n;
      }
      __syncthreads();
    } else {
      if (tid == 0) { rv[jc] = -1e300; ri[jc] = 0x7fffffff; }
    }
  }
  __syncthreads();

  // sort refined 64 descending, emit top-32 with relu
  for (int k = 2; k <= NREF; k <<= 1) {
    for (int j = k >> 1; j > 0; j >>= 1) {
      __syncthreads();
      if (tid < NREF / 2) {
        int i = ((tid & ~(j - 1)) << 1) | (tid & (j - 1));
        int p = i | j;
        bool up = ((i & k) == 0);
        double va = rv[i], vb = rv[p];
        int ia = ri[i], ib = ri[p];
        bool aFirst = (va > vb) || (va == vb && ia < ib);
        if (up ? (!aFirst) : aFirst) {
          rv[i] = vb; rv[p] = va; ri[i] = ib; ri[p] = ia;
        }
      }
    }
  }
  __syncthreads();
  if (tid < KTOP) {
    double v = rv[tid];
    int n = ri[tid];
    float f = (n < NDIR && v > 0.0) ? (float)v : 0.0f;
    sel_val[(size_t)row * KTOP + tid] = f;
    sel_idx[(size_t)row * KTOP + tid] = (n < NDIR) ? n : 0;
  }
}

// ---------------- dec_w [D,N] f32 -> dec_wt [N,D] bf16 ----------------
__global__ void transpose_dec(const float* __restrict__ dec_w, uint16_t* __restrict__ dec_wt) {
  __shared__ float tile[32][33];
  int n0 = blockIdx.x * 32, d0 = blockIdx.y * 32;
  int tx = threadIdx.x, ty = threadIdx.y;
#pragma unroll
  for (int i = 0; i < 4; ++i)
    tile[ty + i * 8][tx] = dec_w[(size_t)(d0 + ty + i * 8) * NDIR + n0 + tx];
  __syncthreads();
#pragma unroll
  for (int i = 0; i < 4; ++i)
    dec_wt[(size_t)(n0 + ty + i * 8) * DMODEL + d0 + tx] = f2bf(tile[tx][ty + i * 8]);
}

// ---------------- sparse decode: block per token ----------------
__global__ __launch_bounds__(256) void decode_k(
    const uint16_t* __restrict__ dec_wt, const float* __restrict__ sel_val,
    const int* __restrict__ sel_idx, const float* __restrict__ pre_bias,
    float* __restrict__ out) {
  __shared__ float vs[KTOP];
  __shared__ int isx[KTOP];
  const int b = blockIdx.x, tid = threadIdx.x;
  if (tid < KTOP) {
    vs[tid] = sel_val[(size_t)b * KTOP + tid];
    isx[tid] = sel_idx[(size_t)b * KTOP + tid];
  }
  __syncthreads();
  const int d = tid * 8;
  float acc[8];
  float4 p0 = *reinterpret_cast<const float4*>(pre_bias + d);
  float4 p1 = *reinterpret_cast<const float4*>(pre_bias + d + 4);
  acc[0] = p0.x; acc[1] = p0.y; acc[2] = p0.z; acc[3] = p0.w;
  acc[4] = p1.x; acc[5] = p1.y; acc[6] = p1.z; acc[7] = p1.w;
#pragma unroll 4
  for (int k = 0; k < KTOP; ++k) {
    float v = vs[k];
    int n = isx[k];
    uint4 raw = *reinterpret_cast<const uint4*>(dec_wt + (size_t)n * DMODEL + d);
    acc[0] += v * bf2f(raw.x & 0xffffu); acc[1] += v * bf2f(raw.x >> 16);
    acc[2] += v * bf2f(raw.y & 0xffffu); acc[3] += v * bf2f(raw.y >> 16);
    acc[4] += v * bf2f(raw.z & 0xffffu); acc[5] += v * bf2f(raw.z >> 16);
    acc[6] += v * bf2f(raw.w & 0xffffu); acc[7] += v * bf2f(raw.w >> 16);
  }
  float4 o0{acc[0], acc[1], acc[2], acc[3]};
  float4 o1{acc[4], acc[5], acc[6], acc[7]};
  *reinterpret_cast<float4*>(out + (size_t)b * DMODEL + d) = o0;
  *reinterpret_cast<float4*>(out + (size_t)b * DMODEL + d + 4) = o1;
}

extern "C" void kernel_launch(void* const* d_in, const int* in_sizes, int n_in,
                              void* d_out, int out_size, void* d_ws, size_t ws_size,
                              hipStream_t stream) {
  const float* x = (const float*)d_in[0];
  const float* enc_w = (const float*)d_in[1];
  const float* dec_w = (const float*)d_in[2];
  const float* pre_bias = (const float*)d_in[3];
  const float* latent_bias = (const float*)d_in[4];
  float* out = (float*)d_out;

  char* ws = (char*)d_ws;
  size_t off = 0;
  uint16_t* xh = (uint16_t*)(ws + off); off += (size_t)B_TOK * DMODEL * 2;     // 32 MiB
  uint16_t* wh = (uint16_t*)(ws + off); off += (size_t)NDIR * DMODEL * 2;      // 128 MiB
  uint16_t* dec_wt = (uint16_t*)(ws + off); off += (size_t)NDIR * DMODEL * 2;  // 128 MiB
  float* cand_val = (float*)(ws + off); off += (size_t)B_TOK * CAP * 4;        // 16 MiB
  int* cand_idx = (int*)(ws + off); off += (size_t)B_TOK * CAP * 4;            // 16 MiB
  int* cand_cnt = (int*)(ws + off); off += (size_t)B_TOK * 4;
  float* sel_val = (float*)(ws + off); off += (size_t)B_TOK * KTOP * 4;
  int* sel_idx = (int*)(ws + off); off += (size_t)B_TOK * KTOP * 4;
  (void)ws_size; (void)in_sizes; (void)n_in; (void)out_size;

  hipMemsetAsync(cand_cnt, 0, (size_t)B_TOK * 4, stream);

  prep_x_k<<<(B_TOK * DMODEL) / (256 * 4), 256, 0, stream>>>(x, pre_bias, xh);
  prep_w_k<<<(NDIR * DMODEL) / (256 * 4), 256, 0, stream>>>(enc_w, wh);
  transpose_dec<<<dim3(NDIR / 32, DMODEL / 32), dim3(32, 8), 0, stream>>>(dec_w, dec_wt);
  gemm_topk<<<(B_TOK / 128) * (NDIR / 128), 256, 0, stream>>>(
      xh, wh, latent_bias, cand_val, cand_idx, cand_cnt);
  select_refine<<<B_TOK, 256, 0, stream>>>(
      x, pre_bias, enc_w, latent_bias, cand_val, cand_idx, cand_cnt, sel_val, sel_idx);
  decode_k<<<B_TOK, 256, 0, stream>>>(dec_wt, sel_val, sel_idx, pre_bias, out);
}

// Round 2
// 2332.654 us; speedup vs baseline: 1.1735x; 1.1735x over previous
//
#include <hip/hip_runtime.h>
#include <stdint.h>

#define B_TOK 8192
#define DMODEL 2048
#define NDIR 32768
#define KTOP 32
#define CAP 512
#define NREF 64
#define THRESH 2.5f

typedef __attribute__((ext_vector_type(8))) short short8;
typedef __attribute__((ext_vector_type(4))) float f32x4;

__device__ __forceinline__ uint16_t f2bf(float f) {
  uint32_t u = __float_as_uint(f);
  u = (u + 0x7fffu + ((u >> 16) & 1u)) >> 16;
  return (uint16_t)u;
}
__device__ __forceinline__ float bf2f(uint32_t u) { return __uint_as_float(u << 16); }

__device__ __forceinline__ void async_load16(const void* g, void* l) {
  __builtin_amdgcn_global_load_lds(
      (const __attribute__((address_space(1))) unsigned int*)g,
      (__attribute__((address_space(3))) unsigned int*)l, 16, 0, 0);
}

// ---------------- prep: fp32 -> bf16 ----------------
__global__ void prep_x_k(const float* __restrict__ x, const float* __restrict__ pre_bias,
                         uint16_t* __restrict__ xh) {
  size_t i = ((size_t)blockIdx.x * blockDim.x + threadIdx.x) * 4;
  float4 v = *reinterpret_cast<const float4*>(x + i);
  int d = (int)(i & (DMODEL - 1));
  float4 p = *reinterpret_cast<const float4*>(pre_bias + d);
  ushort4 o;
  o.x = f2bf(v.x - p.x); o.y = f2bf(v.y - p.y);
  o.z = f2bf(v.z - p.z); o.w = f2bf(v.w - p.w);
  *reinterpret_cast<ushort4*>(xh + i) = o;
}

__global__ void prep_w_k(const float* __restrict__ w, uint16_t* __restrict__ wh) {
  size_t i = ((size_t)blockIdx.x * blockDim.x + threadIdx.x) * 4;
  float4 v = *reinterpret_cast<const float4*>(w + i);
  ushort4 o;
  o.x = f2bf(v.x); o.y = f2bf(v.y); o.z = f2bf(v.z); o.w = f2bf(v.w);
  *reinterpret_cast<ushort4*>(wh + i) = o;
}

// ---------------- 256x256 8-phase bf16 GEMM (T2+T3+T4+T5) + threshold collect ----------------
// BM=BN=256, BK=64, 8 waves (2M x 4N), 512 thr. LDS: buf p at p*65536: A halves at
// +0/+16384, B halves at +32768/+49152. XOR-swizzle: byte col c -> c ^ ((row&7)<<4).
__global__ __launch_bounds__(512, 2) void gemm_topk(
    const uint16_t* __restrict__ xh, const uint16_t* __restrict__ wh,
    const float* __restrict__ latent_bias,
    float* __restrict__ cand_val, int* __restrict__ cand_idx, int* __restrict__ cand_cnt) {
  __shared__ char smem[131072];
  const int tid = threadIdx.x;
  const int w = tid >> 6, l = tid & 63;
  const int lr = l & 15, g = l >> 4;
  const int wm_w = (w >> 2) * 128;  // M-warp: rows wm_w..wm_w+127
  const int wn_w = (w & 3) * 64;    // N-warp: cols wn_w..wn_w+63

  int bid = blockIdx.x;
  int swz = (bid & 7) * 512 + (bid >> 3);  // 4096 wgs, %8==0 -> bijective
  const int bm = swz >> 7, bn = swz & 127;
  const int m0i = bm * 256, n0i = bn * 256;

  const char* Agb = (const char*)xh + (size_t)m0i * 4096;
  const char* Bgb = (const char*)wh + (size_t)n0i * 4096;

  const int key = (lr & 7) << 4;
  const int cx0 = (g << 4) ^ key;         // kk=0 swizzled byte col
  const int cx1 = (64 | (g << 4)) ^ key;  // kk=1

  const char* ArdBase = smem + (wm_w >> 7) * 16384;          // + p*65536
  const char* BrdBase = smem + 32768 + (wn_w >> 7) * 16384;  // + p*65536
  const int bhr = wn_w & 64;  // row base within B half

  f32x4 acc[8][4] = {};
  short8 a[8], b[8];

  auto stage = [&](const char* grow0, char* dst) {
#pragma unroll
    for (int inst = 0; inst < 2; ++inst) {
      int o = inst * 8192 + tid * 16;
      int row = o >> 7;
      int cb = (o & 127) ^ ((row & 7) << 4);  // pre-swizzled global source (rule #21)
      async_load16(grow0 + (size_t)row * 4096 + cb, dst + inst * 8192 + (tid >> 6) * 1024);
    }
  };

  const int NT = DMODEL / 64;  // 32

  // prologue: t0 {A0,A1,B0,B1}, t1 {B0,B1}; wait t0 (leave t1.B in flight)
  stage(Agb, smem);
  stage(Agb + 524288, smem + 16384);
  stage(Bgb, smem + 32768);
  stage(Bgb + 524288, smem + 49152);
  stage(Bgb + 128, smem + 65536 + 32768);
  stage(Bgb + 524288 + 128, smem + 65536 + 49152);
  asm volatile("s_waitcnt vmcnt(4)" ::: "memory");
  __builtin_amdgcn_s_barrier();

  for (int t = 0; t < NT; ++t) {
    const int p = t & 1;
    const char* At = ArdBase + p * 65536;
    const char* Bt = BrdBase + p * 65536;
    char* SA = smem + ((t + 1) & 1) * 65536;  // A dest buf for tile t+1
    char* SB = smem + p * 65536 + 32768;      // B dest buf for tile t+2 ((t+2)&1 == t&1)
    const char* Ag = Agb + (size_t)(t + 1) * 128;
    const char* Bg = Bgb + (size_t)(t + 2) * 128;
    const bool s1 = (t + 1 < NT), s2 = (t + 2 < NT);

    // ---- P1: ds A(m0-3) + B(n0-1); stage (t+1).A0; MFMA q(m0-3 x n0-1)
#pragma unroll
    for (int f = 0; f < 4; ++f) {
      const char* rA = At + (f * 16 + lr) * 128;
      a[f * 2 + 0] = *(const short8*)(rA + cx0);
      a[f * 2 + 1] = *(const short8*)(rA + cx1);
    }
#pragma unroll
    for (int f = 0; f < 2; ++f) {
      const char* rB = Bt + (bhr + f * 16 + lr) * 128;
      b[f * 2 + 0] = *(const short8*)(rB + cx0);
      b[f * 2 + 1] = *(const short8*)(rB + cx1);
    }
    if (s1) stage(Ag, SA);
    __builtin_amdgcn_s_barrier();
    asm volatile("s_waitcnt lgkmcnt(0)" ::: "memory");
    __builtin_amdgcn_s_setprio(1);
#pragma unroll
    for (int fm = 0; fm < 4; ++fm)
#pragma unroll
      for (int fn = 0; fn < 2; ++fn)
#pragma unroll
        for (int kk = 0; kk < 2; ++kk)
          acc[fm][fn] = __builtin_amdgcn_mfma_f32_16x16x32_bf16(a[fm * 2 + kk], b[fn * 2 + kk],
                                                                acc[fm][fn], 0, 0, 0);
    __builtin_amdgcn_s_setprio(0);
    __builtin_amdgcn_s_barrier();

    // ---- P2: ds B(n2-3); stage (t+1).A1; MFMA q(m0-3 x n2-3)
#pragma unroll
    for (int f = 2; f < 4; ++f) {
      const char* rB = Bt + (bhr + f * 16 + lr) * 128;
      b[f * 2 + 0] = *(const short8*)(rB + cx0);
      b[f * 2 + 1] = *(const short8*)(rB + cx1);
    }
    if (s1) stage(Ag + 524288, SA + 16384);
    __builtin_amdgcn_s_barrier();
    asm volatile("s_waitcnt lgkmcnt(0)" ::: "memory");
    __builtin_amdgcn_s_setprio(1);
#pragma unroll
    for (int fm = 0; fm < 4; ++fm)
#pragma unroll
      for (int fn = 2; fn < 4; ++fn)
#pragma unroll
        for (int kk = 0; kk < 2; ++kk)
          acc[fm][fn] = __builtin_amdgcn_mfma_f32_16x16x32_bf16(a[fm * 2 + kk], b[fn * 2 + kk],
                                                                acc[fm][fn], 0, 0, 0);
    __builtin_amdgcn_s_setprio(0);
    __builtin_amdgcn_s_barrier();

    // ---- P3: ds A(m4-7); stage (t+2).B0; MFMA q(m4-7 x n2-3)
#pragma unroll
    for (int f = 0; f < 4; ++f) {
      const char* rA = At + ((f + 4) * 16 + lr) * 128;
      a[f * 2 + 0] = *(const short8*)(rA + cx0);
      a[f * 2 + 1] = *(const short8*)(rA + cx1);
    }
    if (s2) stage(Bg, SB);
    __builtin_amdgcn_s_barrier();
    asm volatile("s_waitcnt lgkmcnt(0)" ::: "memory");
    __builtin_amdgcn_s_setprio(1);
#pragma unroll
    for (int fm = 4; fm < 8; ++fm)
#pragma unroll
      for (int fn = 2; fn < 4; ++fn)
#pragma unroll
        for (int kk = 0; kk < 2; ++kk)
          acc[fm][fn] = __builtin_amdgcn_mfma_f32_16x16x32_bf16(a[(fm - 4) * 2 + kk],
                                                                b[fn * 2 + kk], acc[fm][fn], 0, 0, 0);
    __builtin_amdgcn_s_setprio(0);
    __builtin_amdgcn_s_barrier();

    // ---- P4: stage (t+2).B1; counted vmcnt(4); MFMA q(m4-7 x n0-1)
    if (s2) stage(Bg + 524288, SB + 16384);
    if (t < NT - 2)
      asm volatile("s_waitcnt vmcnt(4)" ::: "memory");
    else
      asm volatile("s_waitcnt vmcnt(0)" ::: "memory");
    __builtin_amdgcn_s_barrier();
    __builtin_amdgcn_s_setprio(1);
#pragma unroll
    for (int fm = 4; fm < 8; ++fm)
#pragma unroll
      for (int fn = 0; fn < 2; ++fn)
#pragma unroll
        for (int kk = 0; kk < 2; ++kk)
          acc[fm][fn] = __builtin_amdgcn_mfma_f32_16x16x32_bf16(a[(fm - 4) * 2 + kk],
                                                                b[fn * 2 + kk], acc[fm][fn], 0, 0, 0);
    __builtin_amdgcn_s_setprio(0);
    __builtin_amdgcn_s_barrier();
  }

  // epilogue: C/D layout col = lane&15 (n), row = (lane>>4)*4 + j (m)
#pragma unroll
  for (int fn = 0; fn < 4; ++fn) {
    int gn = n0i + wn_w + fn * 16 + lr;
    float lb = latent_bias[gn];
#pragma unroll
    for (int fm = 0; fm < 8; ++fm) {
      int gmb = m0i + wm_w + fm * 16 + g * 4;
#pragma unroll
      for (int j = 0; j < 4; ++j) {
        float v = acc[fm][fn][j] + lb;
        if (v > THRESH) {
          int gm = gmb + j;
          int pos = atomicAdd(&cand_cnt[gm], 1);
          if (pos < CAP) {
            cand_val[(size_t)gm * CAP + pos] = v;
            cand_idx[(size_t)gm * CAP + pos] = gn;
          }
        }
      }
    }
  }
}

// ---------------- per-row: sort candidates, fp64-refine top-64, emit exact top-32 ----------------
__global__ __launch_bounds__(256) void select_refine(
    const float* __restrict__ x, const float* __restrict__ pre_bias,
    const float* __restrict__ enc_w, const float* __restrict__ latent_bias,
    const float* __restrict__ cand_val, const int* __restrict__ cand_idx,
    const int* __restrict__ cand_cnt,
    float* __restrict__ sel_val, int* __restrict__ sel_idx) {
  __shared__ float sv[CAP];
  __shared__ int si[CAP];
  __shared__ float xc[DMODEL];
  __shared__ double red[4];
  __shared__ double rv[NREF];
  __shared__ int ri[NREF];

  const int row = blockIdx.x, tid = threadIdx.x;

  for (int d = tid; d < DMODEL; d += 256)
    xc[d] = x[(size_t)row * DMODEL + d] - pre_bias[d];

  int c = cand_cnt[row];
  if (c > CAP) c = CAP;
  for (int i = tid; i < CAP; i += 256) {
    if (i < c) {
      sv[i] = cand_val[(size_t)row * CAP + i];
      si[i] = cand_idx[(size_t)row * CAP + i];
    } else {
      sv[i] = -1e30f;
      si[i] = 0x7fffffff;
    }
  }

  // bitonic sort, descending by (val, then lower idx) — deterministic despite atomic append order
  for (int k = 2; k <= CAP; k <<= 1) {
    for (int j = k >> 1; j > 0; j >>= 1) {
      __syncthreads();
      int i = ((tid & ~(j - 1)) << 1) | (tid & (j - 1));
      int p = i | j;
      bool up = ((i & k) == 0);
      float va = sv[i], vb = sv[p];
      int ia = si[i], ib = si[p];
      bool aFirst = (va > vb) || (va == vb && ia < ib);
      if (up ? (!aFirst) : aFirst) {
        sv[i] = vb; sv[p] = va; si[i] = ib; si[p] = ia;
      }
    }
  }
  __syncthreads();

  const int nref = c < NREF ? c : NREF;
  for (int jc = 0; jc < NREF; ++jc) {
    if (jc < nref) {  // uniform branch
      int n = si[jc];
      const float* wrow = enc_w + (size_t)n * DMODEL;
      double s = 0.0;
      for (int d = tid; d < DMODEL; d += 256)
        s += (double)xc[d] * (double)wrow[d];
#pragma unroll
      for (int off = 32; off > 0; off >>= 1)
        s += __shfl_down(s, off);
      if ((tid & 63) == 0) red[tid >> 6] = s;
      __syncthreads();
      if (tid == 0) {
        rv[jc] = red[0] + red[1] + red[2] + red[3] + (double)latent_bias[n];
        ri[jc] = n;
      }
      __syncthreads();
    } else {
      if (tid == 0) { rv[jc] = -1e300; ri[jc] = 0x7fffffff; }
    }
  }
  __syncthreads();

  // sort refined 64 descending, emit top-32 with relu
  for (int k = 2; k <= NREF; k <<= 1) {
    for (int j = k >> 1; j > 0; j >>= 1) {
      __syncthreads();
      if (tid < NREF / 2) {
        int i = ((tid & ~(j - 1)) << 1) | (tid & (j - 1));
        int p = i | j;
        bool up = ((i & k) == 0);
        double va = rv[i], vb = rv[p];
        int ia = ri[i], ib = ri[p];
        bool aFirst = (va > vb) || (va == vb && ia < ib);
        if (up ? (!aFirst) : aFirst) {
          rv[i] = vb; rv[p] = va; ri[i] = ib; ri[p] = ia;
        }
      }
    }
  }
  __syncthreads();
  if (tid < KTOP) {
    double v = rv[tid];
    int n = ri[tid];
    float f = (n < NDIR && v > 0.0) ? (float)v : 0.0f;
    sel_val[(size_t)row * KTOP + tid] = f;
    sel_idx[(size_t)row * KTOP + tid] = (n < NDIR) ? n : 0;
  }
}

// ---------------- dec_w [D,N] f32 -> dec_wt [N,D] bf16 ----------------
__global__ void transpose_dec(const float* __restrict__ dec_w, uint16_t* __restrict__ dec_wt) {
  __shared__ float tile[32][33];
  int n0 = blockIdx.x * 32, d0 = blockIdx.y * 32;
  int tx = threadIdx.x, ty = threadIdx.y;
#pragma unroll
  for (int i = 0; i < 4; ++i)
    tile[ty + i * 8][tx] = dec_w[(size_t)(d0 + ty + i * 8) * NDIR + n0 + tx];
  __syncthreads();
#pragma unroll
  for (int i = 0; i < 4; ++i)
    dec_wt[(size_t)(n0 + ty + i * 8) * DMODEL + d0 + tx] = f2bf(tile[tx][ty + i * 8]);
}

// ---------------- sparse decode: block per token ----------------
__global__ __launch_bounds__(256) void decode_k(
    const uint16_t* __restrict__ dec_wt, const float* __restrict__ sel_val,
    const int* __restrict__ sel_idx, const float* __restrict__ pre_bias,
    float* __restrict__ out) {
  __shared__ float vs[KTOP];
  __shared__ int isx[KTOP];
  const int b = blockIdx.x, tid = threadIdx.x;
  if (tid < KTOP) {
    vs[tid] = sel_val[(size_t)b * KTOP + tid];
    isx[tid] = sel_idx[(size_t)b * KTOP + tid];
  }
  __syncthreads();
  const int d = tid * 8;
  float acc[8];
  float4 p0 = *reinterpret_cast<const float4*>(pre_bias + d);
  float4 p1 = *reinterpret_cast<const float4*>(pre_bias + d + 4);
  acc[0] = p0.x; acc[1] = p0.y; acc[2] = p0.z; acc[3] = p0.w;
  acc[4] = p1.x; acc[5] = p1.y; acc[6] = p1.z; acc[7] = p1.w;
#pragma unroll 4
  for (int k = 0; k < KTOP; ++k) {
    float v = vs[k];
    int n = isx[k];
    uint4 raw = *reinterpret_cast<const uint4*>(dec_wt + (size_t)n * DMODEL + d);
    acc[0] += v * bf2f(raw.x & 0xffffu); acc[1] += v * bf2f(raw.x >> 16);
    acc[2] += v * bf2f(raw.y & 0xffffu); acc[3] += v * bf2f(raw.y >> 16);
    acc[4] += v * bf2f(raw.z & 0xffffu); acc[5] += v * bf2f(raw.z >> 16);
    acc[6] += v * bf2f(raw.w & 0xffffu); acc[7] += v * bf2f(raw.w >> 16);
  }
  float4 o0{acc[0], acc[1], acc[2], acc[3]};
  float4 o1{acc[4], acc[5], acc[6], acc[7]};
  *reinterpret_cast<float4*>(out + (size_t)b * DMODEL + d) = o0;
  *reinterpret_cast<float4*>(out + (size_t)b * DMODEL + d + 4) = o1;
}

extern "C" void kernel_launch(void* const* d_in, const int* in_sizes, int n_in,
                              void* d_out, int out_size, void* d_ws, size_t ws_size,
                              hipStream_t stream) {
  const float* x = (const float*)d_in[0];
  const float* enc_w = (const float*)d_in[1];
  const float* dec_w = (const float*)d_in[2];
  const float* pre_bias = (const float*)d_in[3];
  const float* latent_bias = (const float*)d_in[4];
  float* out = (float*)d_out;

  char* ws = (char*)d_ws;
  size_t off = 0;
  uint16_t* xh = (uint16_t*)(ws + off); off += (size_t)B_TOK * DMODEL * 2;     // 32 MiB
  uint16_t* wh = (uint16_t*)(ws + off); off += (size_t)NDIR * DMODEL * 2;      // 128 MiB
  uint16_t* dec_wt = (uint16_t*)(ws + off); off += (size_t)NDIR * DMODEL * 2;  // 128 MiB
  float* cand_val = (float*)(ws + off); off += (size_t)B_TOK * CAP * 4;        // 16 MiB
  int* cand_idx = (int*)(ws + off); off += (size_t)B_TOK * CAP * 4;            // 16 MiB
  int* cand_cnt = (int*)(ws + off); off += (size_t)B_TOK * 4;
  float* sel_val = (float*)(ws + off); off += (size_t)B_TOK * KTOP * 4;
  int* sel_idx = (int*)(ws + off); off += (size_t)B_TOK * KTOP * 4;
  (void)ws_size; (void)in_sizes; (void)n_in; (void)out_size;

  hipMemsetAsync(cand_cnt, 0, (size_t)B_TOK * 4, stream);

  prep_x_k<<<(B_TOK * DMODEL) / (256 * 4), 256, 0, stream>>>(x, pre_bias, xh);
  prep_w_k<<<(NDIR * DMODEL) / (256 * 4), 256, 0, stream>>>(enc_w, wh);
  transpose_dec<<<dim3(NDIR / 32, DMODEL / 32), dim3(32, 8), 0, stream>>>(dec_w, dec_wt);
  gemm_topk<<<(B_TOK / 256) * (NDIR / 256), 512, 0, stream>>>(
      xh, wh, latent_bias, cand_val, cand_idx, cand_cnt);
  select_refine<<<B_TOK, 256, 0, stream>>>(
      x, pre_bias, enc_w, latent_bias, cand_val, cand_idx, cand_cnt, sel_val, sel_idx);
  decode_k<<<B_TOK, 256, 0, stream>>>(dec_wt, sel_val, sel_idx, pre_bias, out);
}

// Round 3
// 1999.246 us; speedup vs baseline: 1.3692x; 1.1668x over previous
//
#include <hip/hip_runtime.h>
#include <stdint.h>

#define B_TOK 8192
#define DMODEL 2048
#define NDIR 32768
#define KTOP 32
#define CAP 512
#define BANDCAP 40
#define BAND_DELTA 0.06f
#define THRESH 2.5f

typedef __attribute__((ext_vector_type(8))) short short8;
typedef __attribute__((ext_vector_type(4))) float f32x4;

__device__ __forceinline__ uint16_t f2bf(float f) {
  uint32_t u = __float_as_uint(f);
  u = (u + 0x7fffu + ((u >> 16) & 1u)) >> 16;
  return (uint16_t)u;
}
__device__ __forceinline__ float bf2f(uint32_t u) { return __uint_as_float(u << 16); }

__device__ __forceinline__ void async_load16(const void* g, void* l) {
  __builtin_amdgcn_global_load_lds(
      (const __attribute__((address_space(1))) unsigned int*)g,
      (__attribute__((address_space(3))) unsigned int*)l, 16, 0, 0);
}

// ---------------- prep: fp32 -> bf16 ----------------
__global__ void prep_x_k(const float* __restrict__ x, const float* __restrict__ pre_bias,
                         uint16_t* __restrict__ xh) {
  size_t i = ((size_t)blockIdx.x * blockDim.x + threadIdx.x) * 4;
  float4 v = *reinterpret_cast<const float4*>(x + i);
  int d = (int)(i & (DMODEL - 1));
  float4 p = *reinterpret_cast<const float4*>(pre_bias + d);
  ushort4 o;
  o.x = f2bf(v.x - p.x); o.y = f2bf(v.y - p.y);
  o.z = f2bf(v.z - p.z); o.w = f2bf(v.w - p.w);
  *reinterpret_cast<ushort4*>(xh + i) = o;
}

__global__ void prep_w_k(const float* __restrict__ w, uint16_t* __restrict__ wh) {
  size_t i = ((size_t)blockIdx.x * blockDim.x + threadIdx.x) * 4;
  float4 v = *reinterpret_cast<const float4*>(w + i);
  ushort4 o;
  o.x = f2bf(v.x); o.y = f2bf(v.y); o.z = f2bf(v.z); o.w = f2bf(v.w);
  *reinterpret_cast<ushort4*>(wh + i) = o;
}

// ---------------- 256x256 8-phase bf16 GEMM + read-ahead + threshold collect ----------------
// BM=BN=256, BK=64, 8 waves (2M x 4N), 512 thr. LDS: buf p at p*65536: A halves at
// +0/+16384, B halves at +32768/+49152. XOR-swizzle: byte col c -> c ^ ((row&7)<<4).
// Quadrants: Q1(m0-3,bP) Q2(m0-3,bQ) Q3(m4-7,bP) Q4(m4-7,bQ); ds_reads one phase ahead:
// P1 reads bQ(t), P2 reads aH(t), P4 (after vmcnt+bar) reads aL(t+1),bP(t+1).
__global__ __launch_bounds__(512, 2) void gemm_topk(
    const uint16_t* __restrict__ xh, const uint16_t* __restrict__ wh,
    const float* __restrict__ latent_bias,
    float* __restrict__ cand_val, int* __restrict__ cand_idx, int* __restrict__ cand_cnt) {
  __shared__ char smem[131072];
  const int tid = threadIdx.x;
  const int w = tid >> 6, l = tid & 63;
  const int lr = l & 15, g = l >> 4;
  const int wm_w = (w >> 2) * 128;  // M-warp rows
  const int wn_w = (w & 3) * 64;    // N-warp cols

  int bid = blockIdx.x;
  int swz = (bid & 7) * 512 + (bid >> 3);  // 4096 wgs, %8==0 -> bijective
  const int bm = swz >> 7, bn = swz & 127;
  const int m0i = bm * 256, n0i = bn * 256;

  const char* Agb = (const char*)xh + (size_t)m0i * 4096;
  const char* Bgb = (const char*)wh + (size_t)n0i * 4096;

  const int key = (lr & 7) << 4;
  const int cx0 = (g << 4) ^ key;         // kk=0 swizzled byte col
  const int cx1 = (64 | (g << 4)) ^ key;  // kk=1

  const char* ArdBase = smem + (wm_w >> 7) * 16384;          // + p*65536
  const char* BrdBase = smem + 32768 + (wn_w >> 7) * 16384;  // + p*65536
  const int bhr = wn_w & 64;  // row base within B half

  f32x4 acc[8][4] = {};
  short8 aL[8], aH[8], bP[4], bQ[4];

  auto stage = [&](const char* grow0, char* dst) {
#pragma unroll
    for (int inst = 0; inst < 2; ++inst) {
      int o = inst * 8192 + tid * 16;
      int row = o >> 7;
      int cb = (o & 127) ^ ((row & 7) << 4);  // pre-swizzled global source
      async_load16(grow0 + (size_t)row * 4096 + cb, dst + inst * 8192 + (tid >> 6) * 1024);
    }
  };

  const int NT = DMODEL / 64;  // 32

  // prologue: t0 {A0,A1,B0,B1}, t1 {B0,B1}; wait t0 halves (leave t1.B in flight)
  stage(Agb, smem);
  stage(Agb + 524288, smem + 16384);
  stage(Bgb, smem + 32768);
  stage(Bgb + 524288, smem + 49152);
  stage(Bgb + 128, smem + 65536 + 32768);
  stage(Bgb + 524288 + 128, smem + 65536 + 49152);
  asm volatile("s_waitcnt vmcnt(4)" ::: "memory");
  __builtin_amdgcn_s_barrier();
  // prefetch tile 0: aL (m0-3), bP (n-frags 0,1)
#pragma unroll
  for (int f = 0; f < 4; ++f) {
    const char* rA = ArdBase + (f * 16 + lr) * 128;
    aL[f * 2 + 0] = *(const short8*)(rA + cx0);
    aL[f * 2 + 1] = *(const short8*)(rA + cx1);
  }
#pragma unroll
  for (int f = 0; f < 2; ++f) {
    const char* rB = BrdBase + (bhr + f * 16 + lr) * 128;
    bP[f * 2 + 0] = *(const short8*)(rB + cx0);
    bP[f * 2 + 1] = *(const short8*)(rB + cx1);
  }

  for (int t = 0; t < NT; ++t) {
    const int p = t & 1;
    const char* At = ArdBase + p * 65536;
    const char* Bt = BrdBase + p * 65536;
    char* SA = smem + ((t + 1) & 1) * 65536;  // A dest for tile t+1
    char* SB = smem + p * 65536 + 32768;      // B dest for tile t+2
    const char* Ag = Agb + (size_t)(t + 1) * 128;
    const char* Bg = Bgb + (size_t)(t + 2) * 128;
    const bool s1 = (t + 1 < NT), s2 = (t + 2 < NT);

    // ---- P1: ds bQ(t); stage A(t+1).0; bar; MFMA Q1 = (m0-3) x (n0-1)
#pragma unroll
    for (int f = 0; f < 2; ++f) {
      const char* rB = Bt + (bhr + (f + 2) * 16 + lr) * 128;
      bQ[f * 2 + 0] = *(const short8*)(rB + cx0);
      bQ[f * 2 + 1] = *(const short8*)(rB + cx1);
    }
    if (s1) stage(Ag, SA);
    __builtin_amdgcn_s_barrier();
    __builtin_amdgcn_s_setprio(1);
#pragma unroll
    for (int fm = 0; fm < 4; ++fm)
#pragma unroll
      for (int fn = 0; fn < 2; ++fn)
#pragma unroll
        for (int kk = 0; kk < 2; ++kk)
          acc[fm][fn] = __builtin_amdgcn_mfma_f32_16x16x32_bf16(aL[fm * 2 + kk], bP[fn * 2 + kk],
                                                                acc[fm][fn], 0, 0, 0);
    __builtin_amdgcn_s_setprio(0);
    __builtin_amdgcn_s_barrier();

    // ---- P2: ds aH(t); stage A(t+1).1; bar; MFMA Q2 = (m0-3) x (n2-3)
#pragma unroll
    for (int f = 0; f < 4; ++f) {
      const char* rA = At + ((f + 4) * 16 + lr) * 128;
      aH[f * 2 + 0] = *(const short8*)(rA + cx0);
      aH[f * 2 + 1] = *(const short8*)(rA + cx1);
    }
    if (s1) stage(Ag + 524288, SA + 16384);
    __builtin_amdgcn_s_barrier();
    __builtin_amdgcn_s_setprio(1);
#pragma unroll
    for (int fm = 0; fm < 4; ++fm)
#pragma unroll
      for (int fn = 2; fn < 4; ++fn)
#pragma unroll
        for (int kk = 0; kk < 2; ++kk)
          acc[fm][fn] = __builtin_amdgcn_mfma_f32_16x16x32_bf16(aL[fm * 2 + kk],
                                                                bQ[(fn - 2) * 2 + kk],
                                                                acc[fm][fn], 0, 0, 0);
    __builtin_amdgcn_s_setprio(0);
    __builtin_amdgcn_s_barrier();

    // ---- P3: stage B(t+2).0; bar; MFMA Q3 = (m4-7) x (n0-1)
    if (s2) stage(Bg, SB);
    __builtin_amdgcn_s_barrier();
    __builtin_amdgcn_s_setprio(1);
#pragma unroll
    for (int fm = 4; fm < 8; ++fm)
#pragma unroll
      for (int fn = 0; fn < 2; ++fn)
#pragma unroll
        for (int kk = 0; kk < 2; ++kk)
          acc[fm][fn] = __builtin_amdgcn_mfma_f32_16x16x32_bf16(aH[(fm - 4) * 2 + kk],
                                                                bP[fn * 2 + kk], acc[fm][fn], 0, 0, 0);
    __builtin_amdgcn_s_setprio(0);
    __builtin_amdgcn_s_barrier();

    // ---- P4: stage B(t+2).1; vmcnt; bar; prefetch aL/bP of t+1; MFMA Q4 = (m4-7) x (n2-3)
    if (s2) stage(Bg + 524288, SB + 16384);
    if (t < NT - 2)
      asm volatile("s_waitcnt vmcnt(4)" ::: "memory");
    else
      asm volatile("s_waitcnt vmcnt(0)" ::: "memory");
    __builtin_amdgcn_s_barrier();
    if (t + 1 < NT) {
      const char* An = ArdBase + ((t + 1) & 1) * 65536;
      const char* Bn = BrdBase + ((t + 1) & 1) * 65536;
#pragma unroll
      for (int f = 0; f < 4; ++f) {
        const char* rA = An + (f * 16 + lr) * 128;
        aL[f * 2 + 0] = *(const short8*)(rA + cx0);
        aL[f * 2 + 1] = *(const short8*)(rA + cx1);
      }
#pragma unroll
      for (int f = 0; f < 2; ++f) {
        const char* rB = Bn + (bhr + f * 16 + lr) * 128;
        bP[f * 2 + 0] = *(const short8*)(rB + cx0);
        bP[f * 2 + 1] = *(const short8*)(rB + cx1);
      }
    }
    __builtin_amdgcn_s_setprio(1);
#pragma unroll
    for (int fm = 4; fm < 8; ++fm)
#pragma unroll
      for (int fn = 2; fn < 4; ++fn)
#pragma unroll
        for (int kk = 0; kk < 2; ++kk)
          acc[fm][fn] = __builtin_amdgcn_mfma_f32_16x16x32_bf16(aH[(fm - 4) * 2 + kk],
                                                                bQ[(fn - 2) * 2 + kk],
                                                                acc[fm][fn], 0, 0, 0);
    __builtin_amdgcn_s_setprio(0);
    __builtin_amdgcn_s_barrier();
  }

  // epilogue: C/D layout col = lane&15 (n), row = (lane>>4)*4 + j (m)
#pragma unroll
  for (int fn = 0; fn < 4; ++fn) {
    int gn = n0i + wn_w + fn * 16 + lr;
    float lb = latent_bias[gn];
#pragma unroll
    for (int fm = 0; fm < 8; ++fm) {
      int gmb = m0i + wm_w + fm * 16 + g * 4;
#pragma unroll
      for (int j = 0; j < 4; ++j) {
        float v = acc[fm][fn][j] + lb;
        if (v > THRESH) {
          int gm = gmb + j;
          int pos = atomicAdd(&cand_cnt[gm], 1);
          if (pos < CAP) {
            cand_val[(size_t)gm * CAP + pos] = v;
            cand_idx[(size_t)gm * CAP + pos] = gn;
          }
        }
      }
    }
  }
}

// ---------------- per-row: sort cands; refine {ranks<32} + band; exact top-32 ----------------
__global__ __launch_bounds__(256) void select_refine(
    const float* __restrict__ x, const float* __restrict__ pre_bias,
    const float* __restrict__ enc_w, const float* __restrict__ latent_bias,
    const float* __restrict__ cand_val, const int* __restrict__ cand_idx,
    const int* __restrict__ cand_cnt,
    float* __restrict__ sel_val, int* __restrict__ sel_idx) {
  __shared__ float sv[CAP];
  __shared__ int si[CAP];
  __shared__ float xc[DMODEL];
  __shared__ double rall[128];
  __shared__ int iall[128];
  __shared__ int pext[BANDCAP];
  __shared__ int nex;

  const int row = blockIdx.x, tid = threadIdx.x;
  const int l = tid & 63, wv = tid >> 6;

  for (int d = tid; d < DMODEL; d += 256)
    xc[d] = x[(size_t)row * DMODEL + d] - pre_bias[d];
  if (tid == 0) nex = 0;

  int c = cand_cnt[row];
  if (c > CAP) c = CAP;
  for (int i = tid; i < CAP; i += 256) {
    if (i < c) {
      sv[i] = cand_val[(size_t)row * CAP + i];
      si[i] = cand_idx[(size_t)row * CAP + i];
    } else {
      sv[i] = -1e30f;
      si[i] = 0x7fffffff;
    }
  }

  // bitonic sort desc by (val, lower idx) over CAP=512
  for (int k = 2; k <= CAP; k <<= 1) {
    for (int j = k >> 1; j > 0; j >>= 1) {
      __syncthreads();
      int i = ((tid & ~(j - 1)) << 1) | (tid & (j - 1));
      int p = i | j;
      bool up = ((i & k) == 0);
      float va = sv[i], vb = sv[p];
      int ia = si[i], ib = si[p];
      bool aFirst = (va > vb) || (va == vb && ia < ib);
      if (up ? (!aFirst) : aFirst) {
        sv[i] = vb; sv[p] = va; si[i] = ib; si[p] = ia;
      }
    }
  }
  __syncthreads();

  const float v32a = sv[31];
  // band members at ranks [32,96): within BAND_DELTA of rank-32 approx value
  if (tid >= 32 && tid < 96) {
    float v = sv[tid];
    if (v > -1e29f && si[tid] < NDIR && fabsf(v - v32a) <= BAND_DELTA) {
      int s = atomicAdd(&nex, 1);
      if (s < BANDCAP) pext[s] = tid;
    }
  }
  // pad refine array
  for (int e = tid; e < 128; e += 256) {
    rall[e] = -1e300;
    iall[e] = 0x7fffffff;
  }
  __syncthreads();

  const int ne = nex < BANDCAP ? nex : BANDCAP;
  const int nall = 32 + ne;
  // exact fp64 dots, one candidate per wave, strided
  for (int e = wv; e < nall; e += 4) {
    int pos = (e < 32) ? e : pext[e - 32];
    int n = si[pos];
    if (n < NDIR) {
      const float* wrow = enc_w + (size_t)n * DMODEL;
      double s = 0.0;
#pragma unroll
      for (int u = 0; u < 32; ++u)
        s += (double)xc[u * 64 + l] * (double)wrow[u * 64 + l];
#pragma unroll
      for (int off = 32; off > 0; off >>= 1)
        s += __shfl_down(s, off);
      if (l == 0) {
        rall[e] = s + (double)latent_bias[n];
        iall[e] = n;
      }
    }
  }
  __syncthreads();

  // bitonic sort desc over 128 exact values
  for (int k = 2; k <= 128; k <<= 1) {
    for (int j = k >> 1; j > 0; j >>= 1) {
      __syncthreads();
      if (tid < 64) {
        int i = ((tid & ~(j - 1)) << 1) | (tid & (j - 1));
        int p = i | j;
        bool up = ((i & k) == 0);
        double va = rall[i], vb = rall[p];
        int ia = iall[i], ib = iall[p];
        bool aFirst = (va > vb) || (va == vb && ia < ib);
        if (up ? (!aFirst) : aFirst) {
          rall[i] = vb; rall[p] = va; iall[i] = ib; iall[p] = ia;
        }
      }
    }
  }
  __syncthreads();

  if (tid < KTOP) {
    double v = rall[tid];
    int n = iall[tid];
    float f = (n < NDIR && v > 0.0) ? (float)v : 0.0f;
    sel_val[(size_t)row * KTOP + tid] = f;
    sel_idx[(size_t)row * KTOP + tid] = (n < NDIR) ? n : 0;
  }
}

// ---------------- dec_w [D,N] f32 -> dec_wt [N,D] bf16 ----------------
__global__ void transpose_dec(const float* __restrict__ dec_w, uint16_t* __restrict__ dec_wt) {
  __shared__ float tile[32][33];
  int n0 = blockIdx.x * 32, d0 = blockIdx.y * 32;
  int tx = threadIdx.x, ty = threadIdx.y;
#pragma unroll
  for (int i = 0; i < 4; ++i)
    tile[ty + i * 8][tx] = dec_w[(size_t)(d0 + ty + i * 8) * NDIR + n0 + tx];
  __syncthreads();
#pragma unroll
  for (int i = 0; i < 4; ++i)
    dec_wt[(size_t)(n0 + ty + i * 8) * DMODEL + d0 + tx] = f2bf(tile[tx][ty + i * 8]);
}

// ---------------- sparse decode: block per token ----------------
__global__ __launch_bounds__(256) void decode_k(
    const uint16_t* __restrict__ dec_wt, const float* __restrict__ sel_val,
    const int* __restrict__ sel_idx, const float* __restrict__ pre_bias,
    float* __restrict__ out) {
  __shared__ float vs[KTOP];
  __shared__ int isx[KTOP];
  const int b = blockIdx.x, tid = threadIdx.x;
  if (tid < KTOP) {
    vs[tid] = sel_val[(size_t)b * KTOP + tid];
    isx[tid] = sel_idx[(size_t)b * KTOP + tid];
  }
  __syncthreads();
  const int d = tid * 8;
  float acc[8];
  float4 p0 = *reinterpret_cast<const float4*>(pre_bias + d);
  float4 p1 = *reinterpret_cast<const float4*>(pre_bias + d + 4);
  acc[0] = p0.x; acc[1] = p0.y; acc[2] = p0.z; acc[3] = p0.w;
  acc[4] = p1.x; acc[5] = p1.y; acc[6] = p1.z; acc[7] = p1.w;
#pragma unroll 4
  for (int k = 0; k < KTOP; ++k) {
    float v = vs[k];
    int n = isx[k];
    uint4 raw = *reinterpret_cast<const uint4*>(dec_wt + (size_t)n * DMODEL + d);
    acc[0] += v * bf2f(raw.x & 0xffffu); acc[1] += v * bf2f(raw.x >> 16);
    acc[2] += v * bf2f(raw.y & 0xffffu); acc[3] += v * bf2f(raw.y >> 16);
    acc[4] += v * bf2f(raw.z & 0xffffu); acc[5] += v * bf2f(raw.z >> 16);
    acc[6] += v * bf2f(raw.w & 0xffffu); acc[7] += v * bf2f(raw.w >> 16);
  }
  float4 o0{acc[0], acc[1], acc[2], acc[3]};
  float4 o1{acc[4], acc[5], acc[6], acc[7]};
  *reinterpret_cast<float4*>(out + (size_t)b * DMODEL + d) = o0;
  *reinterpret_cast<float4*>(out + (size_t)b * DMODEL + d + 4) = o1;
}

extern "C" void kernel_launch(void* const* d_in, const int* in_sizes, int n_in,
                              void* d_out, int out_size, void* d_ws, size_t ws_size,
                              hipStream_t stream) {
  const float* x = (const float*)d_in[0];
  const float* enc_w = (const float*)d_in[1];
  const float* dec_w = (const float*)d_in[2];
  const float* pre_bias = (const float*)d_in[3];
  const float* latent_bias = (const float*)d_in[4];
  float* out = (float*)d_out;

  char* ws = (char*)d_ws;
  size_t off = 0;
  uint16_t* xh = (uint16_t*)(ws + off); off += (size_t)B_TOK * DMODEL * 2;     // 32 MiB
  uint16_t* wh = (uint16_t*)(ws + off); off += (size_t)NDIR * DMODEL * 2;      // 128 MiB
  uint16_t* dec_wt = (uint16_t*)(ws + off); off += (size_t)NDIR * DMODEL * 2;  // 128 MiB
  float* cand_val = (float*)(ws + off); off += (size_t)B_TOK * CAP * 4;        // 16 MiB
  int* cand_idx = (int*)(ws + off); off += (size_t)B_TOK * CAP * 4;            // 16 MiB
  int* cand_cnt = (int*)(ws + off); off += (size_t)B_TOK * 4;
  float* sel_val = (float*)(ws + off); off += (size_t)B_TOK * KTOP * 4;
  int* sel_idx = (int*)(ws + off); off += (size_t)B_TOK * KTOP * 4;
  (void)ws_size; (void)in_sizes; (void)n_in; (void)out_size;

  hipMemsetAsync(cand_cnt, 0, (size_t)B_TOK * 4, stream);

  prep_x_k<<<(B_TOK * DMODEL) / (256 * 4), 256, 0, stream>>>(x, pre_bias, xh);
  prep_w_k<<<(NDIR * DMODEL) / (256 * 4), 256, 0, stream>>>(enc_w, wh);
  transpose_dec<<<dim3(NDIR / 32, DMODEL / 32), dim3(32, 8), 0, stream>>>(dec_w, dec_wt);
  gemm_topk<<<(B_TOK / 256) * (NDIR / 256), 512, 0, stream>>>(
      xh, wh, latent_bias, cand_val, cand_idx, cand_cnt);
  select_refine<<<B_TOK, 256, 0, stream>>>(
      x, pre_bias, enc_w, latent_bias, cand_val, cand_idx, cand_cnt, sel_val, sel_idx);
  decode_k<<<B_TOK, 256, 0, stream>>>(dec_wt, sel_val, sel_idx, pre_bias, out);
}